// Round 19
// baseline (495.399 us; speedup 1.0000x reference)
//
#include <hip/hip_runtime.h>
#include <hip/hip_bf16.h>
#include <math.h>

// Problem constants (match reference)
#define BB 4
#define PP 32768
#define TOPK 5000
#define NB 4096
#define NBK 20
#define TBPI 210         // NBK*(NBK+1)/2 triangular tile pairs
#define BMW 160          // bitmap words per (full) row
#define TRIW 411872u     // packed triangular bitmap words per image

// ws layout (bytes). End 3,695,232 (+<=1.1KB read overrun) <= 3,742,720 proven.
// HIST and CNT adjacent -> ONE memset covers both (131,072 B @ 400256).
#define NV_OFF     0u
#define NC_OFF     64u
#define CS_OFF     256u         // float[BB*TOPK]  = 80,000
#define CB_OFF     80256u       // float4[BB*TOPK] = 320,000 (ends 400,256)
#define HIST_OFF   400256u      // uint[BB*NB]
#define CNT_OFF    465792u      // uint[BB*NB]
#define START_OFF  531328u      // uint[BB*NB]
#define GIDX_OFF   596864u      // uint[BB*PP]
#define GSC_OFF    1121152u     // float[BB*PP] (ends 1,645,440)
#define BM_OFF     400256u      // uint[2*TRIW] = 3,294,976 (ends 3,695,232)
#define WS_NEEDED  3742720u

typedef const __attribute__((address_space(1))) unsigned GU1;

// packed row start (words): toff(r) = 160r - 16q(q-1) - (r&31)q, q=r>>5.
// Row r stores original words [q,160): original word w at toff(r)+(w-q).
__device__ __forceinline__ unsigned toffw(unsigned r) {
    unsigned q = r >> 5, s = r & 31u;
    return r * 160u - 16u * q * (q - 1u) - s * q;
}

// Also zeroes d_out (float2-wide) as a side job.
__global__ __launch_bounds__(256) void score_hist_kernel(
    const float2* __restrict__ conf, unsigned* __restrict__ hist,
    float2* __restrict__ outz, int outn2)
{
    int i = blockIdx.x * 256 + threadIdx.x;
    if (i < outn2) outz[i] = make_float2(0.0f, 0.0f);
    if (i >= BB * PP) return;
    int b = i >> 15;
    float s = conf[i].y;
    if (s > 0.05f) {
        int bk = (int)(s * 4096.0f);
        bk = bk < 0 ? 0 : (bk > NB - 1 ? NB - 1 : bk);
        atomicAdd(&hist[b * NB + bk], 1u);
    }
}

__global__ __launch_bounds__(256) void scan_hist_kernel(
    const unsigned* __restrict__ hist, unsigned* __restrict__ start,
    int* __restrict__ nvalid, int* __restrict__ ncand)
{
    int b = blockIdx.x;
    int t = threadIdx.x;
    __shared__ unsigned sums[256];
    unsigned local[16];
    unsigned s = 0;
    const unsigned* hb = hist + b * NB;
    #pragma unroll
    for (int k = 0; k < 16; k++) {
        unsigned v = hb[t * 16 + k];
        local[k] = s;
        s += v;
    }
    sums[t] = s;
    __syncthreads();
    for (int off = 1; off < 256; off <<= 1) {
        unsigned v = (t >= off) ? sums[t - off] : 0u;
        __syncthreads();
        sums[t] += v;
        __syncthreads();
    }
    unsigned excl = sums[t] - s;
    unsigned* sb = start + b * NB;
    #pragma unroll
    for (int k = 0; k < 16; k++) sb[t * 16 + k] = excl + local[k];
    if (t == 255) {
        nvalid[b] = (int)sums[255];
        ncand[b] = sums[255] < (unsigned)TOPK ? (int)sums[255] : TOPK;
    }
}

__global__ __launch_bounds__(256) void scatter_group_kernel(
    const float2* __restrict__ conf, const unsigned* __restrict__ start,
    unsigned* __restrict__ cnt, unsigned* __restrict__ gidx,
    float* __restrict__ gscore)
{
    int i = blockIdx.x * 256 + threadIdx.x;
    if (i >= BB * PP) return;
    int b = i >> 15;
    int p = i & (PP - 1);
    float s = conf[i].y;
    if (s > 0.05f) {
        int bk = (int)(s * 4096.0f);
        bk = bk < 0 ? 0 : (bk > NB - 1 ? NB - 1 : bk);
        unsigned o = atomicAdd(&cnt[b * NB + bk], 1u);
        unsigned pos = start[b * NB + bk] + o;
        gidx[b * PP + pos] = (unsigned)p;
        gscore[b * PP + pos] = s;
    }
}

__global__ __launch_bounds__(256) void rank_topk_kernel(
    const unsigned* __restrict__ gidx, const float* __restrict__ gscore,
    const unsigned* __restrict__ start, const unsigned* __restrict__ hist,
    const int* __restrict__ nvalid, const float4* __restrict__ loc,
    const float4* __restrict__ prior,
    float* __restrict__ cs, float4* __restrict__ cb)
{
#pragma clang fp contract(off)
    int i = blockIdx.x * 256 + threadIdx.x;
    if (i >= BB * PP) return;
    int b = i >> 15;
    int pos = i & (PP - 1);
    int nv = nvalid[b];
    if (pos >= nv) return;
    float s = gscore[b * PP + pos];
    unsigned p = gidx[b * PP + pos];
    int bk = (int)(s * 4096.0f);
    bk = bk < 0 ? 0 : (bk > NB - 1 ? NB - 1 : bk);
    unsigned st = start[b * NB + bk];
    unsigned c = hist[b * NB + bk];
    unsigned rank = (unsigned)nv - st - c;
    const float* gs = gscore + b * PP + st;
    const unsigned* gi = gidx + b * PP + st;
    for (unsigned k = 0; k < c; k++) {
        float sk = gs[k];
        unsigned pk = gi[k];
        if (sk > s || (sk == s && pk < p)) rank++;
    }
    if (rank < (unsigned)TOPK) {
        float4 l = loc[b * PP + (int)p];
        float4 pr = prior[p];
        float cx = pr.x + (l.x * 0.1f) * pr.z;
        float cy = pr.y + (l.y * 0.1f) * pr.w;
        float w = pr.z * expf(l.z * 0.2f);
        float h = pr.w * expf(l.w * 0.2f);
        float4 bx;
        bx.x = cx - 0.5f * w;
        bx.y = cy - 0.5f * h;
        bx.z = cx + 0.5f * w;
        bx.w = cy + 0.5f * h;
        cs[b * TOPK + rank] = s;
        cb[(size_t)b * TOPK + rank] = bx;
    }
}

// Suppressor-major PACKED bitmap, two images per launch. Proven r7-r18.
__global__ __launch_bounds__(256) void bitmap_pair_kernel(
    const float4* __restrict__ cb, int img_base, unsigned* __restrict__ bitmap)
{
#pragma clang fp contract(off)
    int p = blockIdx.x / TBPI;
    int t_ = blockIdx.x % TBPI;
    int img = img_base + p;
    unsigned* bmp = bitmap + (size_t)p * TRIW;

    int bi = (int)((sqrtf(8.0f * (float)t_ + 1.0f) - 1.0f) * 0.5f);
    while ((bi + 1) * (bi + 2) / 2 <= t_) bi++;
    while (bi * (bi + 1) / 2 > t_) bi--;
    int bj = t_ - bi * (bi + 1) / 2;

    const float4* cbb = cb + (size_t)img * TOPK;

    __shared__ float4 jb[256];
    __shared__ float ja[256];
    int tid = threadIdx.x;
    int cg = bi * 256 + tid;
    if (cg < TOPK) {
        float4 v = cbb[cg];
        jb[tid] = v;
        ja[tid] = (v.z - v.x) * (v.w - v.y);
    }
    __syncthreads();

    int r = bj * 256 + tid;
    if (r >= TOPK) return;
    float4 bx = cbb[r];
    float areaR = (bx.z - bx.x) * (bx.w - bx.y);
    bool diag = (bi == bj);

    unsigned wds[8];
    #pragma unroll
    for (int w8 = 0; w8 < 8; w8++) {
        unsigned m = 0u;
        int cb0 = w8 * 32;
        for (int k = 0; k < 32; k++) {
            int cl = cb0 + k;
            int c = bi * 256 + cl;
            if (c >= TOPK) break;
            if (diag && c <= r) continue;      // strict upper triangle
            float4 cc = jb[cl];
            float iw = fminf(bx.z, cc.z) - fmaxf(bx.x, cc.x);
            iw = fmaxf(iw, 0.0f);
            float ih = fminf(bx.w, cc.w) - fmaxf(bx.y, cc.y);
            ih = fmaxf(ih, 0.0f);
            float inter = iw * ih;
            float uni = (ja[cl] + areaR) - inter;
            if (inter / uni > 0.3f) m |= (1u << k);
        }
        wds[w8] = m;
    }
    unsigned q = (unsigned)r >> 5;
    unsigned basew = toffw((unsigned)r) - q + 8u * (unsigned)bi;
    int c0 = diag ? (int)(q - 8u * (unsigned)bj) : 0;
    for (int c = c0; c < 8; c++) bmp[basew + (unsigned)c] = wds[c];
}

// 128-CANDIDATE-GROUP decide/fold (40 phases): wave0 = scalar greedy over a
// 128-bit A (two 64-bit sub-loops, index order preserved); lanes hold rows
// lane & lane+64. Waves 1-11 fold 12 rows each (2 named body bufs, WAR-safe
// reload each phase) + separate 2-deep dia-load stream. Carry = 4 words.
// Packed-layout garbage only hits already-decided lower bits (triangular).
__global__ __launch_bounds__(768, 1) void solve128_kernel(
    const float* __restrict__ cs, const float4* __restrict__ cb,
    const int* __restrict__ ncand, int img_base,
    const unsigned* __restrict__ bitmap, float* __restrict__ out)
{
    int tid = threadIdx.x;
    int wv = tid >> 6;
    int lane = tid & 63;
    int img = img_base + blockIdx.x;
    int nc = ncand[img];
    const unsigned* bm = bitmap + (size_t)blockIdx.x * TRIW;

    __shared__ __align__(16) unsigned Rl[BMW];
    __shared__ __align__(16) unsigned diab[2][128][8];   // 8 KiB
    __shared__ unsigned kw[BMW];
    __shared__ unsigned pref[BMW];

    for (int w = tid; w < BMW; w += 768) {
        kw[w] = 0u;
        int lo = w * 32;
        unsigned m;
        if (lo >= nc) m = 0xffffffffu;
        else if (lo + 32 <= nc) m = 0u;
        else m = ~((1u << (nc - lo)) - 1u);
        Rl[w] = m;
    }

    int ng = (nc + 127) >> 7;
    int rbase = (wv - 1) * 12;               // fold rows [rbase, rbase+12)
    unsigned l4 = (unsigned)lane << 2;
    uint4 bbufE[12], bbufO[12];
    uint4 diaE, diaO;
    unsigned carry0 = 0u, carry1 = 0u, carry2 = 0u, carry3 = 0u;

#define RLN_(V, J) ((unsigned)__builtin_amdgcn_readlane((int)(V), (J)))
#define RFL_(V)    ((unsigned)__builtin_amdgcn_readfirstlane((int)(V)))

#define BODYLOAD(BUF, G) do {                                               \
    int g_ = (G);                                                           \
    if (g_ < ng) {                                                          \
        _Pragma("unroll")                                                   \
        for (int rr = 0; rr < 12; rr++) {                                   \
            int rl_ = rbase + rr;                                           \
            if (rl_ < 128) {                                                \
                int j_ = g_ * 128 + rl_;                                    \
                unsigned jc_ = (unsigned)(j_ < nc ? j_ : nc - 1);           \
                unsigned q_ = jc_ >> 5;                                     \
                GU1* p_ = (GU1*)(bm + (toffw(jc_) - q_ + l4));              \
                BUF[rr].x = p_[0]; BUF[rr].y = p_[1];                       \
                BUF[rr].z = p_[2]; BUF[rr].w = p_[3];                       \
            }                                                               \
        }                                                                   \
    }                                                                       \
} while (0)

#define DIALOAD(DREG, G) do {                                               \
    int g_ = (G);                                                           \
    if (g_ < ng && lane < 24) {                                             \
        int rl_ = rbase + (lane >> 1);                                      \
        if (rl_ < 128) {                                                    \
            int j_ = g_ * 128 + rl_;                                        \
            unsigned jc_ = (unsigned)(j_ < nc ? j_ : nc - 1);               \
            unsigned q_ = jc_ >> 5;                                         \
            unsigned wb_ = 4u * (unsigned)g_ + 4u * (unsigned)(lane & 1);   \
            GU1* p_ = (GU1*)(bm + (toffw(jc_) + wb_ - q_));                 \
            DREG.x = p_[0]; DREG.y = p_[1];                                 \
            DREG.z = p_[2]; DREG.w = p_[3];                                 \
        }                                                                   \
    }                                                                       \
} while (0)

#define DIASTAGE(DREG, G) do {                                              \
    int g_ = (G);                                                           \
    if (g_ < ng && lane < 24) {                                             \
        int rl_ = rbase + (lane >> 1);                                      \
        if (rl_ < 128)                                                      \
            *(uint4*)&diab[g_ & 1][rl_][4 * (lane & 1)] = DREG;             \
    }                                                                       \
} while (0)

#define FOLD(BUF, W) do {                                                   \
    int wp_ = (W) - 1;                                                      \
    if (wp_ >= 0 && wp_ < ng) {                                             \
        unsigned kv0_ = kw[4 * wp_ + 0], kv1_ = kw[4 * wp_ + 1];            \
        unsigned kv2_ = kw[4 * wp_ + 2], kv3_ = kw[4 * wp_ + 3];            \
        uint4 acc_; acc_.x = acc_.y = acc_.z = acc_.w = 0u;                 \
        _Pragma("unroll")                                                   \
        for (int rr = 0; rr < 12; rr++) {                                   \
            int rl_ = rbase + rr;                                           \
            if (rl_ < 128) {                                                \
                unsigned sel_ = (unsigned)rl_ >> 5;                         \
                unsigned kv_ = sel_ == 0u ? kv0_ : sel_ == 1u ? kv1_        \
                             : sel_ == 2u ? kv2_ : kv3_;                    \
                unsigned b_ = (kv_ >> (rl_ & 31)) & 1u;                     \
                unsigned m_ = 0u - b_;                                      \
                acc_.x |= BUF[rr].x & m_; acc_.y |= BUF[rr].y & m_;         \
                acc_.z |= BUF[rr].z & m_; acc_.w |= BUF[rr].w & m_;         \
            }                                                               \
        }                                                                   \
        if (lane < 40) {                                                    \
            if (acc_.x) atomicOr(&Rl[l4 + 0], acc_.x);                      \
            if (acc_.y) atomicOr(&Rl[l4 + 1], acc_.y);                      \
            if (acc_.z) atomicOr(&Rl[l4 + 2], acc_.z);                      \
            if (acc_.w) atomicOr(&Rl[l4 + 3], acc_.w);                      \
        }                                                                   \
    }                                                                       \
} while (0)

#define DECIDE(W) do {                                                      \
    int w_ = (W);                                                           \
    int par_ = w_ & 1;                                                      \
    uint4 ig0_ = *(const uint4*)&diab[par_][lane][0];                       \
    uint4 nx0_ = *(const uint4*)&diab[par_][lane][4];                       \
    uint4 ig1_ = *(const uint4*)&diab[par_][lane + 64][0];                  \
    uint4 nx1_ = *(const uint4*)&diab[par_][lane + 64][4];                  \
    unsigned g0_ = Rl[4 * w_ + 0] | carry0;                                 \
    unsigned g1_ = Rl[4 * w_ + 1] | carry1;                                 \
    unsigned g2_ = Rl[4 * w_ + 2] | carry2;                                 \
    unsigned g3_ = Rl[4 * w_ + 3] | carry3;                                 \
    unsigned long long A0_ =                                                \
        ~((((unsigned long long)RFL_(g1_)) << 32) | RFL_(g0_));             \
    unsigned long long A1_ =                                                \
        ~((((unsigned long long)RFL_(g3_)) << 32) | RFL_(g2_));             \
    unsigned m0lo_ = ig0_.x, m0hi_ = ig0_.y, m1lo_ = ig0_.z, m1hi_ = ig0_.w;\
    unsigned s1lo_ = ig1_.z, s1hi_ = ig1_.w;                                \
    if (lane < 32) { m0lo_ |= 1u << lane; s1lo_ |= 1u << lane; }            \
    else { m0hi_ |= 1u << (lane & 31); s1hi_ |= 1u << (lane & 31); }        \
    unsigned long long K0_ = 0ull, K1_ = 0ull;                              \
    while (A0_) {                                                           \
        int j_ = __builtin_ctzll(A0_);                                      \
        unsigned long long mm0_ =                                           \
            (((unsigned long long)RLN_(m0hi_, j_)) << 32) | RLN_(m0lo_, j_);\
        unsigned long long mm1_ =                                           \
            (((unsigned long long)RLN_(m1hi_, j_)) << 32) | RLN_(m1lo_, j_);\
        K0_ |= 1ull << j_;                                                  \
        A0_ &= ~mm0_;                                                       \
        A1_ &= ~mm1_;                                                       \
    }                                                                       \
    while (A1_) {                                                           \
        int j_ = __builtin_ctzll(A1_);                                      \
        unsigned long long mm1_ =                                           \
            (((unsigned long long)RLN_(s1hi_, j_)) << 32) | RLN_(s1lo_, j_);\
        K1_ |= 1ull << j_;                                                  \
        A1_ &= ~mm1_;                                                       \
    }                                                                       \
    if (lane == 0) {                                                        \
        kw[4 * w_ + 0] = (unsigned)K0_;                                     \
        kw[4 * w_ + 1] = (unsigned)(K0_ >> 32);                             \
        kw[4 * w_ + 2] = (unsigned)K1_;                                     \
        kw[4 * w_ + 3] = (unsigned)(K1_ >> 32);                             \
    }                                                                       \
    unsigned ka_ = (unsigned)((K0_ >> lane) & 1ull);                        \
    unsigned kb_ = (unsigned)((K1_ >> lane) & 1ull);                        \
    unsigned ma_ = 0u - ka_, mb_ = 0u - kb_;                                \
    unsigned c0_ = (nx0_.x & ma_) | (nx1_.x & mb_);                         \
    unsigned c1_ = (nx0_.y & ma_) | (nx1_.y & mb_);                         \
    unsigned c2_ = (nx0_.z & ma_) | (nx1_.z & mb_);                         \
    unsigned c3_ = (nx0_.w & ma_) | (nx1_.w & mb_);                         \
    _Pragma("unroll")                                                       \
    for (int mm_ = 32; mm_; mm_ >>= 1) {                                    \
        c0_ |= __shfl_xor(c0_, mm_);                                        \
        c1_ |= __shfl_xor(c1_, mm_);                                        \
        c2_ |= __shfl_xor(c2_, mm_);                                        \
        c3_ |= __shfl_xor(c3_, mm_);                                        \
    }                                                                       \
    carry0 = RFL_(c0_); carry1 = RFL_(c1_);                                 \
    carry2 = RFL_(c2_); carry3 = RFL_(c3_);                                 \
} while (0)

#define PHASE(W, BBUF, DREG) do {                                           \
    int wph_ = (W);                                                         \
    if (wv == 0) {                                                          \
        if (wph_ < ng) DECIDE(wph_);                                        \
    } else {                                                                \
        FOLD(BBUF, wph_);                                                   \
        DIASTAGE(DREG, wph_ + 1);                                           \
        BODYLOAD(BBUF, wph_ + 1);                                           \
        DIALOAD(DREG, wph_ + 3);                                            \
    }                                                                       \
    asm volatile("s_waitcnt lgkmcnt(0)" ::: "memory");                      \
    __builtin_amdgcn_s_barrier();                                           \
} while (0)

    // prologue
    if (wv > 0) {
        BODYLOAD(bbufE, 0);
        DIALOAD(diaE, 0);
        DIALOAD(diaO, 1);
    }
    __syncthreads();
    if (wv > 0) {
        DIASTAGE(diaE, 0);
        DIALOAD(diaE, 2);
    }
    __syncthreads();

    for (int w = 0; w < ng; w += 2) {
        PHASE(w, bbufO, diaO);       // even phases use odd-group buffers
        PHASE(w + 1, bbufE, diaE);   // odd phases use even-group buffers
    }
#undef BODYLOAD
#undef DIALOAD
#undef DIASTAGE
#undef FOLD
#undef DECIDE
#undef PHASE

    __syncthreads();
    if (tid == 0) {
        unsigned s = 0;
        for (int w = 0; w < BMW; w++) { pref[w] = s; s += __popc(kw[w]); }
    }
    __syncthreads();

    const float* csb = cs + img * TOPK;
    const float4* cbb = cb + (size_t)img * TOPK;
    float* outb = out + ((size_t)img * 2 + 1) * TOPK * 5;
    for (int i = tid; i < nc; i += 768) {
        unsigned w = kw[i >> 5];
        if ((w >> (i & 31)) & 1u) {
            unsigned pos = pref[i >> 5] + __popc(w & ((1u << (i & 31)) - 1u));
            float4 bx = cbb[i];
            float* row = outb + (size_t)pos * 5;
            row[0] = csb[i];
            row[1] = bx.x;
            row[2] = bx.y;
            row[3] = bx.z;
            row[4] = bx.w;
        }
    }
}

extern "C" void kernel_launch(void* const* d_in, const int* in_sizes, int n_in,
                              void* d_out, int out_size, void* d_ws, size_t ws_size,
                              hipStream_t stream) {
    if (ws_size < WS_NEEDED) return;  // fail loudly rather than corrupt

    const float4* loc = (const float4*)d_in[0];
    const float2* conf = (const float2*)d_in[1];
    const float4* prior = (const float4*)d_in[2];
    float* out = (float*)d_out;

    char* ws = (char*)d_ws;
    int* nvalid = (int*)(ws + NV_OFF);
    int* ncand = (int*)(ws + NC_OFF);
    float* cs = (float*)(ws + CS_OFF);
    float4* cb = (float4*)(ws + CB_OFF);
    unsigned* hist = (unsigned*)(ws + HIST_OFF);
    unsigned* cnt = (unsigned*)(ws + CNT_OFF);
    unsigned* start = (unsigned*)(ws + START_OFF);
    unsigned* gidx = (unsigned*)(ws + GIDX_OFF);
    float* gscore = (float*)(ws + GSC_OFF);
    unsigned* bitmap = (unsigned*)(ws + BM_OFF);  // 2 packed images

    // single memset: hist + cnt are adjacent (131,072 B)
    hipMemsetAsync(hist, 0, 2u * BB * NB * sizeof(unsigned), stream);

    int nblk = (BB * PP + 255) / 256;
    score_hist_kernel<<<nblk, 256, 0, stream>>>(conf, hist, (float2*)out,
                                                out_size / 2);
    scan_hist_kernel<<<BB, 256, 0, stream>>>(hist, start, nvalid, ncand);
    scatter_group_kernel<<<nblk, 256, 0, stream>>>(conf, start, cnt, gidx, gscore);
    rank_topk_kernel<<<nblk, 256, 0, stream>>>(gidx, gscore, start, hist, nvalid,
                                               loc, prior, cs, cb);
    for (int g = 0; g < 2; ++g) {
        bitmap_pair_kernel<<<2 * TBPI, 256, 0, stream>>>(cb, 2 * g, bitmap);
        solve128_kernel<<<2, 768, 0, stream>>>(cs, cb, ncand, 2 * g, bitmap, out);
    }
}

// Round 20
// 345.252 us; speedup vs baseline: 1.4349x; 1.4349x over previous
//
#include <hip/hip_runtime.h>
#include <hip/hip_bf16.h>
#include <math.h>

// Problem constants (match reference)
#define BB 4
#define PP 32768
#define TOPK 5000
#define NB 4096
#define NBK 20
#define TBPI 210         // NBK*(NBK+1)/2 triangular tile pairs
#define BMW 160          // bitmap words per (full) row
#define TRIW 411872u     // packed triangular bitmap words per image

// ws layout (bytes). End 3,695,232 (+<=1.1KB read overrun) <= 3,742,720 proven.
// HIST and CNT adjacent -> ONE memset covers both (131,072 B @ 400256).
#define NV_OFF     0u
#define NC_OFF     64u
#define CS_OFF     256u         // float[BB*TOPK]  = 80,000
#define CB_OFF     80256u       // float4[BB*TOPK] = 320,000 (ends 400,256)
#define HIST_OFF   400256u      // uint[BB*NB]
#define CNT_OFF    465792u      // uint[BB*NB]
#define START_OFF  531328u      // uint[BB*NB]
#define GIDX_OFF   596864u      // uint[BB*PP]
#define GSC_OFF    1121152u     // float[BB*PP] (ends 1,645,440)
#define BM_OFF     400256u      // uint[2*TRIW] = 3,294,976 (ends 3,695,232)
#define WS_NEEDED  3742720u

typedef const __attribute__((address_space(1))) unsigned GU1;

// packed row start (words): toff(r) = 160r - 16q(q-1) - (r&31)q, q=r>>5.
// Row r stores original words [q,160): original word w at toff(r)+(w-q).
__device__ __forceinline__ unsigned toffw(unsigned r) {
    unsigned q = r >> 5, s = r & 31u;
    return r * 160u - 16u * q * (q - 1u) - s * q;
}

// Also zeroes d_out (float2-wide) as a side job (saves one memset dispatch).
__global__ __launch_bounds__(256) void score_hist_kernel(
    const float2* __restrict__ conf, unsigned* __restrict__ hist,
    float2* __restrict__ outz, int outn2)
{
    int i = blockIdx.x * 256 + threadIdx.x;
    if (i < outn2) outz[i] = make_float2(0.0f, 0.0f);
    if (i >= BB * PP) return;
    int b = i >> 15;
    float s = conf[i].y;
    if (s > 0.05f) {
        int bk = (int)(s * 4096.0f);
        bk = bk < 0 ? 0 : (bk > NB - 1 ? NB - 1 : bk);
        atomicAdd(&hist[b * NB + bk], 1u);
    }
}

__global__ __launch_bounds__(256) void scan_hist_kernel(
    const unsigned* __restrict__ hist, unsigned* __restrict__ start,
    int* __restrict__ nvalid, int* __restrict__ ncand)
{
    int b = blockIdx.x;
    int t = threadIdx.x;
    __shared__ unsigned sums[256];
    unsigned local[16];
    unsigned s = 0;
    const unsigned* hb = hist + b * NB;
    #pragma unroll
    for (int k = 0; k < 16; k++) {
        unsigned v = hb[t * 16 + k];
        local[k] = s;
        s += v;
    }
    sums[t] = s;
    __syncthreads();
    for (int off = 1; off < 256; off <<= 1) {
        unsigned v = (t >= off) ? sums[t - off] : 0u;
        __syncthreads();
        sums[t] += v;
        __syncthreads();
    }
    unsigned excl = sums[t] - s;
    unsigned* sb = start + b * NB;
    #pragma unroll
    for (int k = 0; k < 16; k++) sb[t * 16 + k] = excl + local[k];
    if (t == 255) {
        nvalid[b] = (int)sums[255];
        ncand[b] = sums[255] < (unsigned)TOPK ? (int)sums[255] : TOPK;
    }
}

__global__ __launch_bounds__(256) void scatter_group_kernel(
    const float2* __restrict__ conf, const unsigned* __restrict__ start,
    unsigned* __restrict__ cnt, unsigned* __restrict__ gidx,
    float* __restrict__ gscore)
{
    int i = blockIdx.x * 256 + threadIdx.x;
    if (i >= BB * PP) return;
    int b = i >> 15;
    int p = i & (PP - 1);
    float s = conf[i].y;
    if (s > 0.05f) {
        int bk = (int)(s * 4096.0f);
        bk = bk < 0 ? 0 : (bk > NB - 1 ? NB - 1 : bk);
        unsigned o = atomicAdd(&cnt[b * NB + bk], 1u);
        unsigned pos = start[b * NB + bk] + o;
        gidx[b * PP + pos] = (unsigned)p;
        gscore[b * PP + pos] = s;
    }
}

__global__ __launch_bounds__(256) void rank_topk_kernel(
    const unsigned* __restrict__ gidx, const float* __restrict__ gscore,
    const unsigned* __restrict__ start, const unsigned* __restrict__ hist,
    const int* __restrict__ nvalid, const float4* __restrict__ loc,
    const float4* __restrict__ prior,
    float* __restrict__ cs, float4* __restrict__ cb)
{
#pragma clang fp contract(off)
    int i = blockIdx.x * 256 + threadIdx.x;
    if (i >= BB * PP) return;
    int b = i >> 15;
    int pos = i & (PP - 1);
    int nv = nvalid[b];
    if (pos >= nv) return;
    float s = gscore[b * PP + pos];
    unsigned p = gidx[b * PP + pos];
    int bk = (int)(s * 4096.0f);
    bk = bk < 0 ? 0 : (bk > NB - 1 ? NB - 1 : bk);
    unsigned st = start[b * NB + bk];
    unsigned c = hist[b * NB + bk];
    unsigned rank = (unsigned)nv - st - c;
    const float* gs = gscore + b * PP + st;
    const unsigned* gi = gidx + b * PP + st;
    for (unsigned k = 0; k < c; k++) {
        float sk = gs[k];
        unsigned pk = gi[k];
        if (sk > s || (sk == s && pk < p)) rank++;
    }
    if (rank < (unsigned)TOPK) {
        float4 l = loc[b * PP + (int)p];
        float4 pr = prior[p];
        float cx = pr.x + (l.x * 0.1f) * pr.z;
        float cy = pr.y + (l.y * 0.1f) * pr.w;
        float w = pr.z * expf(l.z * 0.2f);
        float h = pr.w * expf(l.w * 0.2f);
        float4 bx;
        bx.x = cx - 0.5f * w;
        bx.y = cy - 0.5f * h;
        bx.z = cx + 0.5f * w;
        bx.w = cy + 0.5f * h;
        cs[b * TOPK + rank] = s;
        cb[(size_t)b * TOPK + rank] = bx;
    }
}

// Suppressor-major PACKED bitmap, two images per launch. Proven r7-r19.
__global__ __launch_bounds__(256) void bitmap_pair_kernel(
    const float4* __restrict__ cb, int img_base, unsigned* __restrict__ bitmap)
{
#pragma clang fp contract(off)
    int p = blockIdx.x / TBPI;
    int t_ = blockIdx.x % TBPI;
    int img = img_base + p;
    unsigned* bmp = bitmap + (size_t)p * TRIW;

    int bi = (int)((sqrtf(8.0f * (float)t_ + 1.0f) - 1.0f) * 0.5f);
    while ((bi + 1) * (bi + 2) / 2 <= t_) bi++;
    while (bi * (bi + 1) / 2 > t_) bi--;
    int bj = t_ - bi * (bi + 1) / 2;

    const float4* cbb = cb + (size_t)img * TOPK;

    __shared__ float4 jb[256];
    __shared__ float ja[256];
    int tid = threadIdx.x;
    int cg = bi * 256 + tid;
    if (cg < TOPK) {
        float4 v = cbb[cg];
        jb[tid] = v;
        ja[tid] = (v.z - v.x) * (v.w - v.y);
    }
    __syncthreads();

    int r = bj * 256 + tid;
    if (r >= TOPK) return;
    float4 bx = cbb[r];
    float areaR = (bx.z - bx.x) * (bx.w - bx.y);
    bool diag = (bi == bj);

    unsigned wds[8];
    #pragma unroll
    for (int w8 = 0; w8 < 8; w8++) {
        unsigned m = 0u;
        int cb0 = w8 * 32;
        for (int k = 0; k < 32; k++) {
            int cl = cb0 + k;
            int c = bi * 256 + cl;
            if (c >= TOPK) break;
            if (diag && c <= r) continue;      // strict upper triangle
            float4 cc = jb[cl];
            float iw = fminf(bx.z, cc.z) - fmaxf(bx.x, cc.x);
            iw = fmaxf(iw, 0.0f);
            float ih = fminf(bx.w, cc.w) - fmaxf(bx.y, cc.y);
            ih = fmaxf(ih, 0.0f);
            float inter = iw * ih;
            float uni = (ja[cl] + areaR) - inter;
            if (inter / uni > 0.3f) m |= (1u << k);
        }
        wds[w8] = m;
    }
    unsigned q = (unsigned)r >> 5;
    unsigned basew = toffw((unsigned)r) - q + 8u * (unsigned)bi;
    int c0 = diag ? (int)(q - 8u * (unsigned)bj) : 0;
    for (int c = c0; c < 8; c++) bmp[basew + (unsigned)c] = wds[c];
}

// PROVEN r16/r17 solve (97 us): scalar-chain decide + atomic-free private-
// slice fold, 64-candidate groups, in-register carry, one raw barrier/phase.
__global__ __launch_bounds__(576, 1) void solve_scalar_kernel(
    const float* __restrict__ cs, const float4* __restrict__ cb,
    const int* __restrict__ ncand, int img_base,
    const unsigned* __restrict__ bitmap, float* __restrict__ out)
{
    int tid = threadIdx.x;
    int wv = tid >> 6;
    int lane = tid & 63;
    int img = img_base + blockIdx.x;
    int nc = ncand[img];
    const unsigned* bm = bitmap + (size_t)blockIdx.x * TRIW;

    __shared__ __align__(16) unsigned Rl8[8][BMW];   // private fold slices
    __shared__ __align__(16) unsigned diab[2][64][4];
    __shared__ unsigned kw[BMW];
    __shared__ unsigned pref[BMW];

    for (int w = tid; w < BMW; w += 576) {
        kw[w] = 0u;
        int lo = w * 32;
        unsigned m;
        if (lo >= nc) m = 0xffffffffu;
        else if (lo + 32 <= nc) m = 0u;
        else m = ~((1u << (nc - lo)) - 1u);
        Rl8[0][w] = m;
    }
    for (int i = tid; i < 7 * BMW; i += 576) Rl8[1 + i / BMW][i % BMW] = 0u;

    int ng = (nc + 63) >> 6;
    unsigned l4 = (unsigned)lane << 2;
    uint4 P0[8], P1[8], P2[8];
    unsigned carry_lo = 0u, carry_hi = 0u;

#define LOADG(BUF, G) do {                                                  \
    int g_ = (G);                                                           \
    if (g_ < ng) {                                                          \
        _Pragma("unroll")                                                   \
        for (int rr = 0; rr < 8; rr++) {                                    \
            int j_ = g_ * 64 + (wv - 1) + 8 * rr;                           \
            unsigned jc_ = (unsigned)(j_ < nc ? j_ : nc - 1);               \
            unsigned q_ = jc_ >> 5;                                         \
            GU1* p_ = (GU1*)(bm + (toffw(jc_) - q_ + l4));                  \
            BUF[rr].x = p_[0]; BUF[rr].y = p_[1];                           \
            BUF[rr].z = p_[2]; BUF[rr].w = p_[3];                           \
        }                                                                   \
    }                                                                       \
} while (0)

// stage rows of group g' (words 2g'..2g'+3) into diab[g'&1][row][0..3]
#define STAGE(SB, G) do {                                                   \
    int g_ = (G);                                                           \
    if (g_ < ng) {                                                          \
        int pa_ = g_ & 1;                                                   \
        if ((g_ & 1) == 0) {                                                \
            int kl_ = g_ >> 1;            /* words 4kl..4kl+3 in lane kl */ \
            if (lane == kl_) {                                              \
                _Pragma("unroll")                                           \
                for (int rr = 0; rr < 8; rr++)                              \
                    *(uint4*)&diab[pa_][(wv - 1) + 8 * rr][0] = SB[rr];     \
            }                                                               \
        } else {                                                            \
            int kl_ = (g_ - 1) >> 1;      /* words 4kl+2..: z,w | x,y */    \
            if (lane == kl_) {                                              \
                _Pragma("unroll")                                           \
                for (int rr = 0; rr < 8; rr++) {                            \
                    int r_ = (wv - 1) + 8 * rr;                             \
                    diab[pa_][r_][0] = SB[rr].z;                            \
                    diab[pa_][r_][1] = SB[rr].w;                            \
                }                                                           \
            }                                                               \
            if (lane == kl_ + 1) {                                          \
                _Pragma("unroll")                                           \
                for (int rr = 0; rr < 8; rr++) {                            \
                    int r_ = (wv - 1) + 8 * rr;                             \
                    diab[pa_][r_][2] = SB[rr].x;                            \
                    diab[pa_][r_][3] = SB[rr].y;                            \
                }                                                           \
            }                                                               \
        }                                                                   \
    }                                                                       \
} while (0)

#define PHASE(W, FB, SB) do {                                               \
    int w_ = (W);                                                           \
    if (wv == 0) {                                                          \
        int par_ = w_ & 1;                                                  \
        uint2 d01_ = *(const uint2*)&diab[par_][lane][0];                   \
        uint2 d23_ = *(const uint2*)&diab[par_][lane][2];                   \
        unsigned gv_ = 0u;                                                  \
        if (lane < 16) gv_ = Rl8[lane & 7][2 * w_ + (lane >> 3)];           \
        gv_ |= __shfl_xor(gv_, 1);                                          \
        gv_ |= __shfl_xor(gv_, 2);                                          \
        gv_ |= __shfl_xor(gv_, 4);                                          \
        unsigned glo_ = (unsigned)__builtin_amdgcn_readlane((int)gv_, 0);   \
        unsigned ghi_ = (unsigned)__builtin_amdgcn_readlane((int)gv_, 8);   \
        unsigned long long A_ =                                             \
            ~((((unsigned long long)(ghi_ | carry_hi)) << 32)               \
              | (unsigned long long)(glo_ | carry_lo));                     \
        unsigned rlo_ = d01_.x, rhi_ = d01_.y;                              \
        if (lane < 32) rlo_ |= 1u << lane;                                  \
        else           rhi_ |= 1u << (lane & 31);                           \
        unsigned long long K_ = 0ull;                                       \
        while (A_) {                                                        \
            int j_ = __builtin_ctzll(A_);                                   \
            unsigned slo_ = (unsigned)__builtin_amdgcn_readlane((int)rlo_, j_); \
            unsigned shi_ = (unsigned)__builtin_amdgcn_readlane((int)rhi_, j_); \
            K_ |= 1ull << j_;                                               \
            A_ &= ~((((unsigned long long)shi_) << 32)                      \
                    | (unsigned long long)slo_);                            \
        }                                                                   \
        if (lane == 0) {                                                    \
            kw[2 * w_] = (unsigned)K_;                                      \
            kw[2 * w_ + 1] = (unsigned)(K_ >> 32);                          \
        }                                                                   \
        unsigned keep_ = (unsigned)((K_ >> lane) & 1ull);                   \
        unsigned nm_ = 0u - keep_;                                          \
        unsigned nlo_ = d23_.x & nm_, nhi_ = d23_.y & nm_;                  \
        _Pragma("unroll")                                                   \
        for (int mm_ = 32; mm_; mm_ >>= 1) {                                \
            nlo_ |= __shfl_xor(nlo_, mm_);                                  \
            nhi_ |= __shfl_xor(nhi_, mm_);                                  \
        }                                                                   \
        carry_lo = nlo_; carry_hi = nhi_;                                   \
    } else {                                                                \
        if (w_ > 0) {                                                       \
            unsigned klo_ = kw[2 * (w_ - 1)];                               \
            unsigned khi_ = kw[2 * (w_ - 1) + 1];                           \
            unsigned long long Kp_ =                                        \
                (((unsigned long long)khi_) << 32) | klo_;                  \
            uint4 acc_; acc_.x = acc_.y = acc_.z = acc_.w = 0u;             \
            _Pragma("unroll")                                               \
            for (int rr = 0; rr < 8; rr++) {                                \
                int r_ = (wv - 1) + 8 * rr;                                 \
                unsigned a_ = (unsigned)((Kp_ >> r_) & 1ull);               \
                unsigned m_ = 0u - a_;                                      \
                acc_.x |= FB[rr].x & m_; acc_.y |= FB[rr].y & m_;           \
                acc_.z |= FB[rr].z & m_; acc_.w |= FB[rr].w & m_;           \
            }                                                               \
            if (lane < 40) {                                                \
                uint4 cur_ = *(const uint4*)&Rl8[wv - 1][l4];               \
                cur_.x |= acc_.x; cur_.y |= acc_.y;                         \
                cur_.z |= acc_.z; cur_.w |= acc_.w;                         \
                *(uint4*)&Rl8[wv - 1][l4] = cur_;                           \
            }                                                               \
        }                                                                   \
        STAGE(SB, w_ + 1);                                                  \
        LOADG(FB, w_ + 2);                                                  \
    }                                                                       \
    asm volatile("s_waitcnt lgkmcnt(0)" ::: "memory");                      \
    __builtin_amdgcn_s_barrier();                                           \
} while (0)

    if (wv > 0) {
        LOADG(P0, 0);
        LOADG(P1, 1);
    }
    __syncthreads();                 // drain: P0/P1 landed
    if (wv > 0) STAGE(P0, 0);        // dia of group 0 -> parity 0
    __syncthreads();

    for (int w = 0; w < ng; ) {
        PHASE(w, P2, P1); ++w; if (w >= ng) break;
        PHASE(w, P0, P2); ++w; if (w >= ng) break;
        PHASE(w, P1, P0); ++w;
    }
#undef LOADG
#undef STAGE
#undef PHASE

    __syncthreads();
    if (tid == 0) {
        unsigned s = 0;
        for (int w = 0; w < BMW; w++) { pref[w] = s; s += __popc(kw[w]); }
    }
    __syncthreads();

    const float* csb = cs + img * TOPK;
    const float4* cbb = cb + (size_t)img * TOPK;
    float* outb = out + ((size_t)img * 2 + 1) * TOPK * 5;
    for (int i = tid; i < nc; i += 576) {
        unsigned w = kw[i >> 5];
        if ((w >> (i & 31)) & 1u) {
            unsigned pos = pref[i >> 5] + __popc(w & ((1u << (i & 31)) - 1u));
            float4 bx = cbb[i];
            float* row = outb + (size_t)pos * 5;
            row[0] = csb[i];
            row[1] = bx.x;
            row[2] = bx.y;
            row[3] = bx.z;
            row[4] = bx.w;
        }
    }
}

extern "C" void kernel_launch(void* const* d_in, const int* in_sizes, int n_in,
                              void* d_out, int out_size, void* d_ws, size_t ws_size,
                              hipStream_t stream) {
    if (ws_size < WS_NEEDED) return;  // fail loudly rather than corrupt

    const float4* loc = (const float4*)d_in[0];
    const float2* conf = (const float2*)d_in[1];
    const float4* prior = (const float4*)d_in[2];
    float* out = (float*)d_out;

    char* ws = (char*)d_ws;
    int* nvalid = (int*)(ws + NV_OFF);
    int* ncand = (int*)(ws + NC_OFF);
    float* cs = (float*)(ws + CS_OFF);
    float4* cb = (float4*)(ws + CB_OFF);
    unsigned* hist = (unsigned*)(ws + HIST_OFF);
    unsigned* cnt = (unsigned*)(ws + CNT_OFF);
    unsigned* start = (unsigned*)(ws + START_OFF);
    unsigned* gidx = (unsigned*)(ws + GIDX_OFF);
    float* gscore = (float*)(ws + GSC_OFF);
    unsigned* bitmap = (unsigned*)(ws + BM_OFF);  // 2 packed images

    // single memset: hist + cnt are adjacent (131,072 B)
    hipMemsetAsync(hist, 0, 2u * BB * NB * sizeof(unsigned), stream);

    int nblk = (BB * PP + 255) / 256;
    score_hist_kernel<<<nblk, 256, 0, stream>>>(conf, hist, (float2*)out,
                                                out_size / 2);
    scan_hist_kernel<<<BB, 256, 0, stream>>>(hist, start, nvalid, ncand);
    scatter_group_kernel<<<nblk, 256, 0, stream>>>(conf, start, cnt, gidx, gscore);
    rank_topk_kernel<<<nblk, 256, 0, stream>>>(gidx, gscore, start, hist, nvalid,
                                               loc, prior, cs, cb);
    for (int g = 0; g < 2; ++g) {
        bitmap_pair_kernel<<<2 * TBPI, 256, 0, stream>>>(cb, 2 * g, bitmap);
        solve_scalar_kernel<<<2, 576, 0, stream>>>(cs, cb, ncand, 2 * g, bitmap, out);
    }
}